// Round 7
// baseline (89.992 us; speedup 1.0000x reference)
//
#include <hip/hip_runtime.h>

// out[b,co,h,w] = sum_ci dq( conv3x3(x[b,ci], W[ci,co]) + b[ci,co] )
// Bit-exactness contract (verified R3 absmax==0, R4/R6 absmax=1.4e-6):
//   conv = sequential fmaf over k=(kh*3+kw) ascending, seeded from 0;
//   bias added after as plain f32 add; t = y * (float)(15/9); rintf (half-even);
//   dequant+sum: fmaf(q, 0.6f, acc), ci ascending.
// R7: fully unroll the ci loop. R6's dynamic ci loop serialized each iteration
// on a mixed s_load(weights)+ds_read lgkmcnt drain (~16 round-trips/wave).
// Straight-line 16x body lets the scheduler hoist next-iteration loads above
// the current fma chain (partial lgkmcnt waits). launch_bounds (256,6): grid
// only sustains 6.1 blocks/CU, so give the unrolled body an 85-VGPR budget.

constexpr int B_    = 8;
constexpr int CIN   = 16;
constexpr int COUT  = 32;
constexpr int H_    = 112;
constexpr int W_    = 112;
constexpr int TILE  = 8;             // 112 = 14*8
constexpr int HALO  = TILE + 2;      // 10
constexpr int LDSW  = 12;            // stride 12: (r*12+c) mod 32 -> exact 2-way
constexpr int COG   = 8;             // co per wave

__global__ __launch_bounds__(256, 6)
void conv_quant_sum_kernel(const float* __restrict__ x,
                           const float* __restrict__ w,
                           const float* __restrict__ bias,
                           float* __restrict__ out)
{
#pragma clang fp contract(off)
    const float QS = (float)(15.0 / 9.0);   // 1.66666663f
    const float DQ = 0.6f;                  // post-round dequant multiplier

    __shared__ float xs[CIN][HALO][LDSW];   // 16*10*12*4 = 7.68 KB

    const int t   = threadIdx.x;
    const int tx  = t & 7;                  // col in 8x8 tile
    const int ty  = (t >> 3) & 7;           // row in 8x8 tile
    // wave id via readfirstlane -> provably wave-uniform -> weight/bias
    // accesses stay scalar s_loads (R5 lesson: divergent-looking index
    // turns them into per-lane VMEM).
    const int wid = __builtin_amdgcn_readfirstlane(t >> 6);
    const int cog = wid * COG;

    const int tile_x = blockIdx.x * TILE;
    const int tile_y = blockIdx.y * TILE;
    const int b      = blockIdx.z;

    // ---- stage x halo tile (10x10 per ci, zero-padded at borders) ----
    const float* xb = x + (size_t)b * CIN * H_ * W_;
#pragma unroll
    for (int it = 0; it < 7; ++it) {
        int idx = t + it * 256;
        if (idx < CIN * HALO * HALO) {
            int ci  = idx / (HALO * HALO);
            int rem = idx - ci * (HALO * HALO);
            int r   = rem / HALO;
            int c   = rem - r * HALO;
            int gh  = tile_y + r - 1;
            int gw  = tile_x + c - 1;
            float v = 0.0f;
            if ((unsigned)gh < (unsigned)H_ && (unsigned)gw < (unsigned)W_)
                v = xb[ci * H_ * W_ + gh * W_ + gw];
            xs[ci][r][c] = v;
        }
    }
    __syncthreads();

    float acc[COG];
#pragma unroll
    for (int co = 0; co < COG; ++co) acc[co] = 0.0f;

#pragma unroll
    for (int ci = 0; ci < CIN; ++ci) {
        float xv[9];
#pragma unroll
        for (int r = 0; r < 3; ++r)
#pragma unroll
            for (int c = 0; c < 3; ++c)
                xv[r * 3 + c] = xs[ci][ty + r][tx + c];

        const float* wc = w + (ci * COUT + cog) * 9;   // wave-uniform
        const float* bc = bias + ci * COUT + cog;
#pragma unroll
        for (int co = 0; co < COG; ++co) {
            float s = 0.0f;                       // conv seeded from 0
#pragma unroll
            for (int k = 0; k < 9; ++k)
                s = fmaf(xv[k], wc[co * 9 + k], s);
            float y = s + bc[co];                 // bias: separate f32 add
            float q = rintf(y * QS);              // v_rndne_f32, half-even
            acc[co] = fmaf(q, DQ, acc[co]);       // dequant+sum (post-round)
        }
    }

    float* ob = out + ((size_t)b * COUT + cog) * H_ * W_;
    const int oh = tile_y + ty;
    const int ow = tile_x + tx;
#pragma unroll
    for (int co = 0; co < COG; ++co)
        ob[co * H_ * W_ + oh * W_ + ow] = acc[co];
}

extern "C" void kernel_launch(void* const* d_in, const int* in_sizes, int n_in,
                              void* d_out, int out_size, void* d_ws, size_t ws_size,
                              hipStream_t stream)
{
    const float* x    = (const float*)d_in[0];
    const float* w    = (const float*)d_in[1];
    const float* bias = (const float*)d_in[2];
    float* out        = (float*)d_out;

    dim3 grid(W_ / TILE, H_ / TILE, B_);   // (14, 14, 8) = 1568 blocks
    dim3 block(256);
    conv_quant_sum_kernel<<<grid, block, 0, stream>>>(x, w, bias, out);
}